// Round 1
// baseline (1667.160 us; speedup 1.0000x reference)
//
#include <hip/hip_runtime.h>
#include <math.h>

#define WW 8192     // sequence length (FFT axis)
#define CC 256      // channels
#define BB 8        // batch
#define NMODES 256  // kept modes
#define NBLK 8      // block-diagonal blocks
#define BLK 32      // channels per block
#define MT 8        // modes per workgroup (forward kernel)
#define WT 16       // w-pairs per workgroup (inverse kernel)

static __device__ __forceinline__ float gelu_exact(float v) {
    return 0.5f * v * (1.0f + erff(v * 0.70710678118654752f));
}

// tab[k] = (cos(2*pi*k/8192), sin(2*pi*k/8192))
__global__ void build_tab_k(float2* __restrict__ tab) {
    int k = blockIdx.x * blockDim.x + threadIdx.x;
    if (k < WW) {
        float s, c;
        sincospif((float)k * (2.0f / (float)WW), &s, &c);  // sin/cos of pi*(2k/W)
        tab[k] = make_float2(c, s);
    }
}

// Forward truncated DFT (Hermitian-paired) + fused complex block-diag MLP.
// Grid: BB * (NMODES/MT) blocks of 256 threads (thread = channel c).
__launch_bounds__(256, 1)
__global__ void fwd_mlp_k(const float* __restrict__ x,
                          const float* __restrict__ w1,
                          const float* __restrict__ b1,
                          const float* __restrict__ w2,
                          const float* __restrict__ b2,
                          const float2* __restrict__ tab,
                          float2* __restrict__ O) {
    __shared__ float2 stab[WW];          // 64 KiB
    __shared__ float xs[2][MT][CC];      // 16 KiB  (rs-scaled X: re, im)
    __shared__ float o1s[2][MT][CC];     // 16 KiB  (layer-1 activations)

    const int tid = threadIdx.x;
    const int b = blockIdx.x / (NMODES / MT);
    const int m0 = (blockIdx.x % (NMODES / MT)) * MT;

    for (int k = tid; k < WW; k += 256) stab[k] = tab[k];
    __syncthreads();

    const float* xp = x + ((size_t)b * WW) * CC + tid;
    const float x0 = xp[0];
    const float xN = xp[(size_t)4096 * CC];

    float ar[MT], ai[MT];
    int idx[MT];
#pragma unroll
    for (int t = 0; t < MT; ++t) {
        const int m = m0 + t;
        ar[t] = x0 + ((m & 1) ? -xN : xN);   // w=0 and w=4096 (Nyquist-pair) terms
        ai[t] = 0.0f;
        idx[t] = m;                          // (m*1) mod 8192
    }
    // Hermitian pairing: w and 8192-w share |angle|; cos even, sin odd.
#pragma unroll 2
    for (int w = 1; w <= 4095; ++w) {
        const float xa = xp[(size_t)w * CC];
        const float xb = xp[(size_t)(WW - w) * CC];
        const float s = xa + xb;
        const float d = xa - xb;
#pragma unroll
        for (int t = 0; t < MT; ++t) {
            const float2 cs = stab[idx[t]];
            ar[t] = fmaf(s, cs.x, ar[t]);
            ai[t] = fmaf(d, -cs.y, ai[t]);
            idx[t] = (idx[t] + m0 + t) & (WW - 1);
        }
    }

    const float rs = 0.011048543456039806f;  // 1/sqrt(8192)
#pragma unroll
    for (int t = 0; t < MT; ++t) {
        xs[0][t][tid] = ar[t] * rs;
        xs[1][t][tid] = ai[t] * rs;
    }
    __syncthreads();

    // MLP: thread computes output channel (n, oj) for all MT modes.
    const int n = tid >> 5, oj = tid & 31;
    const float* w1r = w1 + (size_t)n * BLK * BLK;            // w1[0][n][i][oj]
    const float* w1i = w1 + (size_t)(NBLK + n) * BLK * BLK;   // w1[1][n][i][oj]
    const float b1r = b1[n * BLK + oj];
    const float b1i = b1[(NBLK + n) * BLK + oj];
#pragma unroll
    for (int t = 0; t < MT; ++t) {
        float sr = b1r, si = b1i;
#pragma unroll 8
        for (int i = 0; i < BLK; ++i) {
            const float xr = xs[0][t][n * BLK + i];
            const float xi = xs[1][t][n * BLK + i];
            const float wr = w1r[i * BLK + oj];
            const float wi = w1i[i * BLK + oj];
            sr = fmaf(xr, wr, sr); sr = fmaf(xi, -wi, sr);
            si = fmaf(xi, wr, si); si = fmaf(xr, wi, si);
        }
        o1s[0][t][tid] = gelu_exact(sr);
        o1s[1][t][tid] = gelu_exact(si);
    }
    __syncthreads();

    const float* w2r = w2 + (size_t)n * BLK * BLK;
    const float* w2i = w2 + (size_t)(NBLK + n) * BLK * BLK;
    const float b2r = b2[n * BLK + oj];
    const float b2i = b2[(NBLK + n) * BLK + oj];
#pragma unroll
    for (int t = 0; t < MT; ++t) {
        float sr = b2r, si = b2i;
#pragma unroll 8
        for (int i = 0; i < BLK; ++i) {
            const float pr = o1s[0][t][n * BLK + i];
            const float pi = o1s[1][t][n * BLK + i];
            const float wr = w2r[i * BLK + oj];
            const float wi = w2i[i * BLK + oj];
            sr = fmaf(pr, wr, sr); sr = fmaf(pi, -wi, sr);
            si = fmaf(pi, wr, si); si = fmaf(pr, wi, si);
        }
        O[((size_t)b * NMODES + m0 + t) * CC + tid] = make_float2(sr, si);
    }
}

// Inverse truncated irfft + residual. numpy irfft ignores Im(DC); Nyquist bin = 0.
// y[w]    = x[w]    + rs*(Or0 + 2*(cacc - sacc))
// y[W-w]  = x[W-w]  + rs*(Or0 + 2*(cacc + sacc))
// cacc = sum_{m>=1} Or[m] cos(2pi m w/W); sacc = sum_{m>=1} Oi[m] sin(2pi m w/W)
// Grid: BB * 257 blocks (w0 = tile*WT covers w in [0,4096]).
__launch_bounds__(256, 2)
__global__ void inv_res_k(const float* __restrict__ x,
                          const float2* __restrict__ tab,
                          const float2* __restrict__ O,
                          float* __restrict__ y) {
    __shared__ float2 stab[WW];  // 64 KiB
    const int tid = threadIdx.x;
    const int NT = (4096 / WT) + 1;  // 257 tiles; last tile handles only w=4096
    const int b = blockIdx.x / NT;
    const int w0 = (blockIdx.x % NT) * WT;

    for (int k = tid; k < WW; k += 256) stab[k] = tab[k];
    __syncthreads();

    const float2* Ob = O + (size_t)b * NMODES * CC + tid;
    const float2 o0 = Ob[0];

    float cacc[WT], sacc[WT];
    int idx[WT];
#pragma unroll
    for (int t = 0; t < WT; ++t) {
        cacc[t] = 0.0f;
        sacc[t] = 0.0f;
        idx[t] = (w0 + t) & (WW - 1);
    }
#pragma unroll 2
    for (int m = 1; m < NMODES; ++m) {
        const float2 om = Ob[(size_t)m * CC];
#pragma unroll
        for (int t = 0; t < WT; ++t) {
            const float2 cs = stab[idx[t]];
            cacc[t] = fmaf(om.x, cs.x, cacc[t]);
            sacc[t] = fmaf(om.y, cs.y, sacc[t]);
            idx[t] = (idx[t] + w0 + t) & (WW - 1);
        }
    }

    const float rs = 0.011048543456039806f;  // 1/sqrt(8192)
    const float* xb = x + ((size_t)b * WW) * CC + tid;
    float* yb = y + ((size_t)b * WW) * CC + tid;
#pragma unroll
    for (int t = 0; t < WT; ++t) {
        const int w = w0 + t;
        if (w > 4096) break;
        const float v1 = o0.x + 2.0f * (cacc[t] - sacc[t]);
        yb[(size_t)w * CC] = fmaf(rs, v1, xb[(size_t)w * CC]);
        if (w >= 1 && w <= 4095) {
            const float v2 = o0.x + 2.0f * (cacc[t] + sacc[t]);
            yb[(size_t)(WW - w) * CC] = fmaf(rs, v2, xb[(size_t)(WW - w) * CC]);
        }
    }
}

extern "C" void kernel_launch(void* const* d_in, const int* in_sizes, int n_in,
                              void* d_out, int out_size, void* d_ws, size_t ws_size,
                              hipStream_t stream) {
    const float* x  = (const float*)d_in[0];
    const float* w1 = (const float*)d_in[1];
    const float* b1 = (const float*)d_in[2];
    const float* w2 = (const float*)d_in[3];
    const float* b2 = (const float*)d_in[4];
    float* out = (float*)d_out;

    // Workspace layout: tab (64 KiB) | O (8*256*256 float2 = 4 MiB)
    float2* tab = (float2*)d_ws;
    float2* O   = (float2*)((char*)d_ws + 65536);

    build_tab_k<<<WW / 256, 256, 0, stream>>>(tab);
    fwd_mlp_k<<<BB * (NMODES / MT), 256, 0, stream>>>(x, w1, b1, w2, b2, tab, O);
    inv_res_k<<<BB * ((4096 / WT) + 1), 256, 0, stream>>>(x, tab, O, out);
}

// Round 2
// 144.165 us; speedup vs baseline: 11.5642x; 11.5642x over previous
//
#include <hip/hip_runtime.h>
#include <math.h>

#define RS 0.011048543456039806f   // 1/sqrt(8192)

typedef short short8 __attribute__((ext_vector_type(8)));
typedef float f32x4 __attribute__((ext_vector_type(4)));

static __device__ __forceinline__ unsigned short f2bf(float f) {
    unsigned int b = __float_as_uint(f);
    b += 0x7FFF + ((b >> 16) & 1);   // RNE
    return (unsigned short)(b >> 16);
}

static __device__ __forceinline__ float gelu_exact(float v) {
    return 0.5f * v * (1.0f + erff(v * 0.70710678118654752f));
}

static __device__ __forceinline__ void gload_lds16(const void* g, void* l) {
    __builtin_amdgcn_global_load_lds((const __attribute__((address_space(1))) void*)g,
                                     (__attribute__((address_space(3))) void*)l, 16, 0, 0);
}

// ---------------------------------------------------------------------------
// Basis builders. Image layout per 128x64 tile (16 KiB): fragment-stream order
//   byte = ((f)*64 + l)*16 + j*2,  f = mi*2 + kk  (mi: 16-row group, kk: 32-k group)
//   row  = mi*16 + (l&15),  k = kk*32 + (l>>4)*8 + j
// A-tiles and B-tiles use the SAME (h,j)->k slot map, so correctness is
// independent of the HW's internal fragment k-permutation.
// ---------------------------------------------------------------------------
__global__ void build_efwd_k(unsigned short* __restrict__ E) {
    const int gid = blockIdx.x * 256 + threadIdx.x;      // 0..524287
    const int l = gid & 63;
    const int f = (gid >> 6) & 15;
    const int T = (gid >> 10) & 127;                     // k-step tile
    const int I = gid >> 17;                             // row tile 0..3
    const int r = I * 128 + (f >> 1) * 16 + (l & 15);    // 0..511
    const int m = r & 255;
    const int w0 = T * 64 + (f & 1) * 32 + ((l >> 4) << 3);
    short8 v;
#pragma unroll
    for (int j = 0; j < 8; ++j) {
        int mw = (m * (w0 + j)) & 8191;
        float s, c;
        sincospif((float)mw * (2.0f / 8192.0f), &s, &c);
        v[j] = (short)f2bf(r < 256 ? RS * c : -RS * s);
    }
    *(short8*)(E + (size_t)gid * 8) = v;
}

__global__ void build_einv_k(unsigned short* __restrict__ E) {
    const int gid = blockIdx.x * 256 + threadIdx.x;      // 0..524287
    const int l = gid & 63;
    const int f = (gid >> 6) & 15;
    const int T = (gid >> 10) & 7;                       // k-step tile 0..7
    const int I = gid >> 13;                             // row tile 0..63
    const int w = I * 128 + (f >> 1) * 16 + (l & 15);    // 0..8191
    const int k0 = T * 64 + (f & 1) * 32 + ((l >> 4) << 3);
    short8 v;
#pragma unroll
    for (int j = 0; j < 8; ++j) {
        const int k = k0 + j;
        const int m = k & 255;
        int mw = (m * w) & 8191;
        float s, c;
        sincospif((float)mw * (2.0f / 8192.0f), &s, &c);
        float val;
        if (k < 256) val = (m == 0 ? 1.0f : 2.0f) * RS * c;   // re plane (DC: x1)
        else         val = (m == 0 ? 0.0f : -2.0f) * RS * s;  // im plane (DC im ignored)
        v[j] = (short)f2bf(val);
    }
    *(short8*)(E + (size_t)gid * 8) = v;
}

// ---------------------------------------------------------------------------
// Forward GEMM: Xp[ks][b][512][256] (f32 partials) = E_fwd[512,K-slice] * x
// grid 256 blocks: bid = ks + 4*I + 16*nt + 32*b. 128x128 tile, BK=64.
// ---------------------------------------------------------------------------
__launch_bounds__(256, 2)
__global__ void fwd_gemm_k(const float* __restrict__ x,
                           const unsigned short* __restrict__ Efwd,
                           float* __restrict__ Xp) {
    __shared__ short8 As8[1024];   // 16 KiB A tile (fragment image)
    __shared__ short8 Bs8[1024];   // 16 KiB B tile (fragment image)
    const int tid = threadIdx.x;
    const int lane = tid & 63, wid = tid >> 6;
    const int bid = blockIdx.x;
    const int ks = bid & 3, I = (bid >> 2) & 3, nt = (bid >> 4) & 1, b = bid >> 5;
    const int c0 = nt * 128;
    const int wr = wid >> 1, wc = wid & 1;
    const int cl = tid & 127, ghalf = tid >> 7;

    f32x4 acc[4][4] = {};

    for (int s = 0; s < 32; ++s) {
        const int T = ks * 32 + s;
        const int k0 = T * 64;
        if (s) __syncthreads();
        // stage A (linear 16 KiB copy, pre-swizzled in global)
        const char* asrc = (const char*)Efwd + (size_t)(I * 128 + T) * 16384;
#pragma unroll
        for (int p = 0; p < 4; ++p)
            gload_lds16(asrc + p * 4096 + tid * 16, (char*)As8 + p * 4096 + wid * 1024);
        // stage B: x fp32 -> bf16 fragment image (8 w per thread, one col)
#pragma unroll
        for (int p = 0; p < 4; ++p) {
            const int g = p * 2 + ghalf;                 // 0..7 (8-w group)
            const float* xr = x + ((size_t)b * 8192 + k0 + g * 8) * 256 + c0 + cl;
            short8 v;
#pragma unroll
            for (int j = 0; j < 8; ++j) v[j] = (short)f2bf(xr[(size_t)j * 256]);
            Bs8[((cl >> 4) * 2 + (g >> 2)) * 64 + (g & 3) * 16 + (cl & 15)] = v;
        }
        __syncthreads();
#pragma unroll
        for (int kk = 0; kk < 2; ++kk) {
            short8 af[4], bf[4];
#pragma unroll
            for (int i = 0; i < 4; ++i) {
                af[i] = As8[((wr * 4 + i) * 2 + kk) * 64 + lane];
                bf[i] = Bs8[((wc * 4 + i) * 2 + kk) * 64 + lane];
            }
#pragma unroll
            for (int mi = 0; mi < 4; ++mi)
#pragma unroll
                for (int ni = 0; ni < 4; ++ni)
                    acc[mi][ni] = __builtin_amdgcn_mfma_f32_16x16x32_bf16(
                        af[mi], bf[ni], acc[mi][ni], 0, 0, 0);
        }
    }
    // epilogue: C/D layout col=lane&15, row=(lane>>4)*4+reg  [m89-verified]
    float* Xpb = Xp + (size_t)(ks * 8 + b) * 512 * 256;
    const int row0 = I * 128 + wr * 64 + ((lane >> 4) << 2);
    const int colb = c0 + wc * 64 + (lane & 15);
#pragma unroll
    for (int mi = 0; mi < 4; ++mi)
#pragma unroll
        for (int ni = 0; ni < 4; ++ni) {
            const int row = row0 + mi * 16;
            const int col = colb + ni * 16;
#pragma unroll
            for (int r = 0; r < 4; ++r)
                Xpb[(size_t)(row + r) * 256 + col] = acc[mi][ni][r];
        }
}

// ---------------------------------------------------------------------------
// MLP: sum 4 partials -> complex block-diag MLP (round-1 verified math) ->
// write O as bf16 directly in the inverse GEMM's B fragment image.
// grid 256 blocks: bid = mgroup + 32*b. O_img[b][nt][T][f][l][j]
// ---------------------------------------------------------------------------
__launch_bounds__(256, 2)
__global__ void mlp_k(const float* __restrict__ Xp,
                      const float* __restrict__ w1, const float* __restrict__ b1,
                      const float* __restrict__ w2, const float* __restrict__ b2,
                      unsigned short* __restrict__ Oimg) {
    __shared__ float xs[2][8][256];
    __shared__ float o1s[2][8][256];
    const int tid = threadIdx.x;
    const int b = blockIdx.x >> 5;
    const int m0 = (blockIdx.x & 31) * 8;

    for (int s = tid; s < 4096; s += 256) {
        const int c = s & 255, t = (s >> 8) & 7, plane = s >> 11;
        const size_t rbase = ((size_t)b * 512 + plane * 256 + m0 + t) * 256 + c;
        float a = 0.0f;
#pragma unroll
        for (int ksp = 0; ksp < 4; ++ksp)
            a += Xp[(size_t)ksp * 8 * 512 * 256 + rbase];
        xs[plane][t][c] = a;
    }
    __syncthreads();

    const int n = tid >> 5, oj = tid & 31;
    const float* w1r = w1 + (size_t)n * 1024;
    const float* w1i = w1 + (size_t)(8 + n) * 1024;
    const float b1r = b1[n * 32 + oj], b1i = b1[(8 + n) * 32 + oj];
#pragma unroll
    for (int t = 0; t < 8; ++t) {
        float sr = b1r, si = b1i;
#pragma unroll 8
        for (int i = 0; i < 32; ++i) {
            const float xr = xs[0][t][n * 32 + i];
            const float xi = xs[1][t][n * 32 + i];
            const float wr = w1r[i * 32 + oj];
            const float wi = w1i[i * 32 + oj];
            sr = fmaf(xr, wr, sr); sr = fmaf(xi, -wi, sr);
            si = fmaf(xi, wr, si); si = fmaf(xr, wi, si);
        }
        o1s[0][t][tid] = gelu_exact(sr);
        o1s[1][t][tid] = gelu_exact(si);
    }
    __syncthreads();

    const float* w2r = w2 + (size_t)n * 1024;
    const float* w2i = w2 + (size_t)(8 + n) * 1024;
    const float b2r = b2[n * 32 + oj], b2i = b2[(8 + n) * 32 + oj];
    const int c = tid;
#pragma unroll
    for (int t = 0; t < 8; ++t) {
        float sr = b2r, si = b2i;
#pragma unroll 8
        for (int i = 0; i < 32; ++i) {
            const float pr = o1s[0][t][n * 32 + i];
            const float pi = o1s[1][t][n * 32 + i];
            const float wr = w2r[i * 32 + oj];
            const float wi = w2i[i * 32 + oj];
            sr = fmaf(pr, wr, sr); sr = fmaf(pi, -wi, sr);
            si = fmaf(pi, wr, si); si = fmaf(pr, wi, si);
        }
        const int m = m0 + t;
#pragma unroll
        for (int plane = 0; plane < 2; ++plane) {
            const int k = plane * 256 + m;
            const float val = plane ? si : sr;
            const size_t off =
                ((((size_t)(b * 2 + (c >> 7)) * 8 + (k >> 6)) * 16 +
                  (((c >> 4) & 7) * 2 + ((k >> 5) & 1))) * 64 +
                 (((k >> 3) & 3) * 16 + (c & 15))) * 16 + (k & 7) * 2;
            *(unsigned short*)((char*)Oimg + off) = f2bf(val);
        }
    }
}

// ---------------------------------------------------------------------------
// Inverse GEMM + residual: out[b,w,c] = x[b,w,c] + sum_k Einv[w,k]*O[b,k,c]
// grid 1024 blocks: bid = nt + 2*I + 128*b. K=512 (8 steps of 64).
// ---------------------------------------------------------------------------
__launch_bounds__(256, 2)
__global__ void inv_gemm_k(const float* __restrict__ x,
                           const unsigned short* __restrict__ Einv,
                           const unsigned short* __restrict__ Oimg,
                           float* __restrict__ out) {
    __shared__ short8 As8[1024];
    __shared__ short8 Bs8[1024];
    const int tid = threadIdx.x;
    const int lane = tid & 63, wid = tid >> 6;
    const int bid = blockIdx.x;
    const int nt = bid & 1, I = (bid >> 1) & 63, b = bid >> 7;
    const int wr = wid >> 1, wc = wid & 1;

    f32x4 acc[4][4] = {};

    for (int T = 0; T < 8; ++T) {
        if (T) __syncthreads();
        const char* asrc = (const char*)Einv + (size_t)(I * 8 + T) * 16384;
        const char* bsrc = (const char*)Oimg + (size_t)((b * 2 + nt) * 8 + T) * 16384;
#pragma unroll
        for (int p = 0; p < 4; ++p) {
            gload_lds16(asrc + p * 4096 + tid * 16, (char*)As8 + p * 4096 + wid * 1024);
            gload_lds16(bsrc + p * 4096 + tid * 16, (char*)Bs8 + p * 4096 + wid * 1024);
        }
        __syncthreads();
#pragma unroll
        for (int kk = 0; kk < 2; ++kk) {
            short8 af[4], bf[4];
#pragma unroll
            for (int i = 0; i < 4; ++i) {
                af[i] = As8[((wr * 4 + i) * 2 + kk) * 64 + lane];
                bf[i] = Bs8[((wc * 4 + i) * 2 + kk) * 64 + lane];
            }
#pragma unroll
            for (int mi = 0; mi < 4; ++mi)
#pragma unroll
                for (int ni = 0; ni < 4; ++ni)
                    acc[mi][ni] = __builtin_amdgcn_mfma_f32_16x16x32_bf16(
                        af[mi], bf[ni], acc[mi][ni], 0, 0, 0);
        }
    }
    const size_t base = (size_t)b * 8192 * 256;
    const int row0 = I * 128 + wr * 64 + ((lane >> 4) << 2);
    const int colb = nt * 128 + wc * 64 + (lane & 15);
#pragma unroll
    for (int mi = 0; mi < 4; ++mi)
#pragma unroll
        for (int ni = 0; ni < 4; ++ni) {
            const int row = row0 + mi * 16;
            const int col = colb + ni * 16;
#pragma unroll
            for (int r = 0; r < 4; ++r) {
                const size_t idx = base + (size_t)(row + r) * 256 + col;
                out[idx] = x[idx] + acc[mi][ni][r];
            }
        }
}

extern "C" void kernel_launch(void* const* d_in, const int* in_sizes, int n_in,
                              void* d_out, int out_size, void* d_ws, size_t ws_size,
                              hipStream_t stream) {
    const float* x  = (const float*)d_in[0];
    const float* w1 = (const float*)d_in[1];
    const float* b1 = (const float*)d_in[2];
    const float* w2 = (const float*)d_in[3];
    const float* b2 = (const float*)d_in[4];
    float* out = (float*)d_out;

    char* ws = (char*)d_ws;
    unsigned short* Efwd = (unsigned short*)(ws);                        // 8 MiB
    unsigned short* Einv = (unsigned short*)(ws + (size_t)(8u << 20));   // 8 MiB
    unsigned short* Oimg = (unsigned short*)(ws + (size_t)(16u << 20));  // 2 MiB
    float*          Xp   = (float*)        (ws + (size_t)(18u << 20));   // 16 MiB

    build_efwd_k<<<2048, 256, 0, stream>>>(Efwd);
    build_einv_k<<<2048, 256, 0, stream>>>(Einv);
    fwd_gemm_k<<<256, 256, 0, stream>>>(x, Efwd, Xp);
    mlp_k<<<256, 256, 0, stream>>>(Xp, w1, b1, w2, b2, Oimg);
    inv_gemm_k<<<1024, 256, 0, stream>>>(x, Einv, Oimg, out);
}

// Round 3
// 108.941 us; speedup vs baseline: 15.3034x; 1.3233x over previous
//
#include <hip/hip_runtime.h>
#include <math.h>

#define RS 0.011048543456039806f   // 1/sqrt(8192)

typedef short short8 __attribute__((ext_vector_type(8)));
typedef float f32x4 __attribute__((ext_vector_type(4)));

static __device__ __forceinline__ unsigned short f2bf(float f) {
    unsigned int b = __float_as_uint(f);
    b += 0x7FFF + ((b >> 16) & 1);   // RNE
    return (unsigned short)(b >> 16);
}
static __device__ __forceinline__ float bf2f(unsigned short u) {
    return __uint_as_float(((unsigned int)u) << 16);
}
static __device__ __forceinline__ float gelu_exact(float v) {
    return 0.5f * v * (1.0f + erff(v * 0.70710678118654752f));
}
static __device__ __forceinline__ void gload_lds16(const void* g, void* l) {
    __builtin_amdgcn_global_load_lds((const __attribute__((address_space(1))) void*)g,
                                     (__attribute__((address_space(3))) void*)l, 16, 0, 0);
}

// ---------------------------------------------------------------------------
// Fragment-image layout per 128x64 tile (16 KiB), shared by ALL operands:
//   byte = (f*64 + l)*16 + j*2,  f = rowgrp*2 + kk
//   row  = rowgrp*16 + (l&15),   k = kk*32 + (l>>4)*8 + j
// A and B tiles use the same (f,l,j)->k slot map, so results are invariant
// to the HW's internal fragment k-permutation.
// ---------------------------------------------------------------------------

// prep: blocks [0,8192): x fp32 -> Xbf bf16 B-image; [8192,10240): Efwd builder.
__global__ void prep_k(const float* __restrict__ x,
                       unsigned short* __restrict__ Xbf,
                       unsigned short* __restrict__ Efwd) {
    const int bid = blockIdx.x;
    const int tid = threadIdx.x;
    if (bid < 8192) {
        const int gid = bid * 256 + tid;                 // 0..2097151
        const int l = gid & 63;
        const int f = (gid >> 6) & 15;
        const int T = (gid >> 10) & 127;
        const int nt = (gid >> 17) & 1;
        const int b = gid >> 18;
        const int w0 = T * 64 + (f & 1) * 32 + ((l >> 4) << 3);
        const int c = nt * 128 + ((f >> 1) << 4) + (l & 15);
        const float* xp = x + ((size_t)b * 8192 + w0) * 256 + c;
        short8 v;
#pragma unroll
        for (int j = 0; j < 8; ++j) v[j] = (short)f2bf(xp[(size_t)j * 256]);
        *(short8*)(Xbf + (size_t)gid * 8) = v;
    } else {
        const int gid = (bid - 8192) * 256 + tid;        // 0..524287
        const int l = gid & 63;
        const int f = (gid >> 6) & 15;
        const int T = (gid >> 10) & 127;                 // k-step tile
        const int I = gid >> 17;                         // row tile 0..3
        const int r = I * 128 + (f >> 1) * 16 + (l & 15);// 0..511
        const int m = r & 255;
        const int w0 = T * 64 + (f & 1) * 32 + ((l >> 4) << 3);
        short8 v;
#pragma unroll
        for (int j = 0; j < 8; ++j) {
            int mw = (m * (w0 + j)) & 8191;
            float s, c;
            sincospif((float)mw * (2.0f / 8192.0f), &s, &c);
            v[j] = (short)f2bf(r < 256 ? RS * c : -RS * s);
        }
        *(short8*)(Efwd + (size_t)gid * 8) = v;
    }
}

__global__ void build_einv_k(unsigned short* __restrict__ E) {
    const int gid = blockIdx.x * 256 + threadIdx.x;      // 0..524287
    const int l = gid & 63;
    const int f = (gid >> 6) & 15;
    const int T = (gid >> 10) & 7;                       // k-step tile 0..7
    const int I = gid >> 13;                             // row tile 0..63
    const int w = I * 128 + (f >> 1) * 16 + (l & 15);    // 0..8191
    const int k0 = T * 64 + (f & 1) * 32 + ((l >> 4) << 3);
    short8 v;
#pragma unroll
    for (int j = 0; j < 8; ++j) {
        const int k = k0 + j;
        const int m = k & 255;
        int mw = (m * w) & 8191;
        float s, c;
        sincospif((float)mw * (2.0f / 8192.0f), &s, &c);
        float val;
        if (k < 256) val = (m == 0 ? 1.0f : 2.0f) * RS * c;   // re plane (DC: x1)
        else         val = (m == 0 ? 0.0f : -2.0f) * RS * s;  // im plane
        v[j] = (short)f2bf(val);
    }
    *(short8*)(E + (size_t)gid * 8) = v;
}

// ---------------------------------------------------------------------------
// Forward GEMM (pure-image): Xp[ks][b][512][256] bf16 = Efwd[512,Kslice]*x
// grid 512: bid = ks + 8*I + 32*nt + 64*b. 128x128 tile, BK=64, 16 K-steps.
// ---------------------------------------------------------------------------
__launch_bounds__(256, 2)
__global__ void fwd_gemm_k(const unsigned short* __restrict__ Xbf,
                           const unsigned short* __restrict__ Efwd,
                           unsigned short* __restrict__ Xp) {
    __shared__ short8 As8[1024];
    __shared__ short8 Bs8[1024];
    const int tid = threadIdx.x;
    const int lane = tid & 63, wid = tid >> 6;
    const int bid = blockIdx.x;
    const int ks = bid & 7, I = (bid >> 3) & 3, nt = (bid >> 5) & 1, b = bid >> 6;
    const int c0 = nt * 128;
    const int wr = wid >> 1, wc = wid & 1;

    f32x4 acc[4][4] = {};

    for (int s = 0; s < 16; ++s) {
        const int T = ks * 16 + s;
        if (s) __syncthreads();
        const char* asrc = (const char*)Efwd + (size_t)(I * 128 + T) * 16384;
        const char* bsrc = (const char*)Xbf + (size_t)((b * 2 + nt) * 128 + T) * 16384;
#pragma unroll
        for (int p = 0; p < 4; ++p) {
            gload_lds16(asrc + p * 4096 + tid * 16, (char*)As8 + p * 4096 + wid * 1024);
            gload_lds16(bsrc + p * 4096 + tid * 16, (char*)Bs8 + p * 4096 + wid * 1024);
        }
        __syncthreads();
#pragma unroll
        for (int kk = 0; kk < 2; ++kk) {
            short8 af[4], bf[4];
#pragma unroll
            for (int i = 0; i < 4; ++i) {
                af[i] = As8[((wr * 4 + i) * 2 + kk) * 64 + lane];
                bf[i] = Bs8[((wc * 4 + i) * 2 + kk) * 64 + lane];
            }
#pragma unroll
            for (int mi = 0; mi < 4; ++mi)
#pragma unroll
                for (int ni = 0; ni < 4; ++ni)
                    acc[mi][ni] = __builtin_amdgcn_mfma_f32_16x16x32_bf16(
                        af[mi], bf[ni], acc[mi][ni], 0, 0, 0);
        }
    }
    // C/D layout: col=lane&15, row=(lane>>4)*4+reg  [m89-verified]
    unsigned short* Xpb = Xp + (size_t)(ks * 8 + b) * 512 * 256;
    const int row0 = I * 128 + wr * 64 + ((lane >> 4) << 2);
    const int colb = c0 + wc * 64 + (lane & 15);
#pragma unroll
    for (int mi = 0; mi < 4; ++mi)
#pragma unroll
        for (int ni = 0; ni < 4; ++ni) {
            const int row = row0 + mi * 16;
            const int col = colb + ni * 16;
#pragma unroll
            for (int r = 0; r < 4; ++r)
                Xpb[(size_t)(row + r) * 256 + col] = f2bf(acc[mi][ni][r]);
        }
}

// ---------------------------------------------------------------------------
// MLP: sum 8 bf16 partials -> complex block-diag MLP -> O as bf16 directly in
// the inverse GEMM's B fragment image. grid 256: bid = mgroup + 32*b.
// ---------------------------------------------------------------------------
__launch_bounds__(256, 2)
__global__ void mlp_k(const unsigned short* __restrict__ Xp,
                      const float* __restrict__ w1, const float* __restrict__ b1,
                      const float* __restrict__ w2, const float* __restrict__ b2,
                      unsigned short* __restrict__ Oimg) {
    __shared__ float xs[2][8][256];
    __shared__ float o1s[2][8][256];
    const int tid = threadIdx.x;
    const int b = blockIdx.x >> 5;
    const int m0 = (blockIdx.x & 31) * 8;

    {   // stage: thread handles 16 consecutive channels of one (plane, t) row
        const int c = (tid * 16) & 255;
        const int t = (tid >> 4) & 7;
        const int plane = tid >> 7;
        float a[16];
#pragma unroll
        for (int j = 0; j < 16; ++j) a[j] = 0.0f;
#pragma unroll
        for (int ksp = 0; ksp < 8; ++ksp) {
            const unsigned short* p =
                Xp + ((size_t)(ksp * 8 + b) * 512 + plane * 256 + m0 + t) * 256 + c;
            const short8 v0 = *(const short8*)p;
            const short8 v1 = *(const short8*)(p + 8);
#pragma unroll
            for (int j = 0; j < 8; ++j) {
                a[j] += bf2f((unsigned short)v0[j]);
                a[8 + j] += bf2f((unsigned short)v1[j]);
            }
        }
#pragma unroll
        for (int j = 0; j < 16; ++j) xs[plane][t][c + j] = a[j];
    }
    __syncthreads();

    const int n = tid >> 5, oj = tid & 31;
    const float* w1r = w1 + (size_t)n * 1024;
    const float* w1i = w1 + (size_t)(8 + n) * 1024;
    const float b1r = b1[n * 32 + oj], b1i = b1[(8 + n) * 32 + oj];
#pragma unroll
    for (int t = 0; t < 8; ++t) {
        float sr = b1r, si = b1i;
#pragma unroll 8
        for (int i = 0; i < 32; ++i) {
            const float xr = xs[0][t][n * 32 + i];
            const float xi = xs[1][t][n * 32 + i];
            const float wr = w1r[i * 32 + oj];
            const float wi = w1i[i * 32 + oj];
            sr = fmaf(xr, wr, sr); sr = fmaf(xi, -wi, sr);
            si = fmaf(xi, wr, si); si = fmaf(xr, wi, si);
        }
        o1s[0][t][tid] = gelu_exact(sr);
        o1s[1][t][tid] = gelu_exact(si);
    }
    __syncthreads();

    const float* w2r = w2 + (size_t)n * 1024;
    const float* w2i = w2 + (size_t)(8 + n) * 1024;
    const float b2r = b2[n * 32 + oj], b2i = b2[(8 + n) * 32 + oj];
    const int c = tid;
#pragma unroll
    for (int t = 0; t < 8; ++t) {
        float sr = b2r, si = b2i;
#pragma unroll 8
        for (int i = 0; i < 32; ++i) {
            const float pr = o1s[0][t][n * 32 + i];
            const float pi = o1s[1][t][n * 32 + i];
            const float wr = w2r[i * 32 + oj];
            const float wi = w2i[i * 32 + oj];
            sr = fmaf(pr, wr, sr); sr = fmaf(pi, -wi, sr);
            si = fmaf(pi, wr, si); si = fmaf(pr, wi, si);
        }
        const int m = m0 + t;
#pragma unroll
        for (int plane = 0; plane < 2; ++plane) {
            const int k = plane * 256 + m;
            const float val = plane ? si : sr;
            const size_t off =
                ((((size_t)(b * 2 + (c >> 7)) * 8 + (k >> 6)) * 16 +
                  (((c >> 4) & 7) * 2 + ((k >> 5) & 1))) * 64 +
                 (((k >> 3) & 3) * 16 + (c & 15))) * 16 + (k & 7) * 2;
            *(unsigned short*)((char*)Oimg + off) = f2bf(val);
        }
    }
}

// ---------------------------------------------------------------------------
// Inverse GEMM + residual. grid 1024: bid = nt + 2*I + 128*b. K=512.
// ---------------------------------------------------------------------------
__launch_bounds__(256, 4)
__global__ void inv_gemm_k(const float* __restrict__ x,
                           const unsigned short* __restrict__ Einv,
                           const unsigned short* __restrict__ Oimg,
                           float* __restrict__ out) {
    __shared__ short8 As8[1024];
    __shared__ short8 Bs8[1024];
    const int tid = threadIdx.x;
    const int lane = tid & 63, wid = tid >> 6;
    const int bid = blockIdx.x;
    const int nt = bid & 1, I = (bid >> 1) & 63, b = bid >> 7;
    const int wr = wid >> 1, wc = wid & 1;

    f32x4 acc[4][4] = {};

    for (int T = 0; T < 8; ++T) {
        if (T) __syncthreads();
        const char* asrc = (const char*)Einv + (size_t)(I * 8 + T) * 16384;
        const char* bsrc = (const char*)Oimg + (size_t)((b * 2 + nt) * 8 + T) * 16384;
#pragma unroll
        for (int p = 0; p < 4; ++p) {
            gload_lds16(asrc + p * 4096 + tid * 16, (char*)As8 + p * 4096 + wid * 1024);
            gload_lds16(bsrc + p * 4096 + tid * 16, (char*)Bs8 + p * 4096 + wid * 1024);
        }
        __syncthreads();
#pragma unroll
        for (int kk = 0; kk < 2; ++kk) {
            short8 af[4], bf[4];
#pragma unroll
            for (int i = 0; i < 4; ++i) {
                af[i] = As8[((wr * 4 + i) * 2 + kk) * 64 + lane];
                bf[i] = Bs8[((wc * 4 + i) * 2 + kk) * 64 + lane];
            }
#pragma unroll
            for (int mi = 0; mi < 4; ++mi)
#pragma unroll
                for (int ni = 0; ni < 4; ++ni)
                    acc[mi][ni] = __builtin_amdgcn_mfma_f32_16x16x32_bf16(
                        af[mi], bf[ni], acc[mi][ni], 0, 0, 0);
        }
    }
    const size_t base = (size_t)b * 8192 * 256;
    const int row0 = I * 128 + wr * 64 + ((lane >> 4) << 2);
    const int colb = nt * 128 + wc * 64 + (lane & 15);
#pragma unroll
    for (int mi = 0; mi < 4; ++mi)
#pragma unroll
        for (int ni = 0; ni < 4; ++ni) {
            const int row = row0 + mi * 16;
            const int col = colb + ni * 16;
#pragma unroll
            for (int r = 0; r < 4; ++r) {
                const size_t idx = base + (size_t)(row + r) * 256 + col;
                out[idx] = x[idx] + acc[mi][ni][r];
            }
        }
}

extern "C" void kernel_launch(void* const* d_in, const int* in_sizes, int n_in,
                              void* d_out, int out_size, void* d_ws, size_t ws_size,
                              hipStream_t stream) {
    const float* x  = (const float*)d_in[0];
    const float* w1 = (const float*)d_in[1];
    const float* b1 = (const float*)d_in[2];
    const float* w2 = (const float*)d_in[3];
    const float* b2 = (const float*)d_in[4];
    float* out = (float*)d_out;

    char* ws = (char*)d_ws;
    // Lifetimes: Xbf,Efwd live during fwd; Oimg reuses Efwd region after fwd;
    // Einv reuses Xbf region after fwd. Peak = 56 MiB.
    unsigned short* Xbf  = (unsigned short*)(ws);                         // 32 MiB
    unsigned short* Efwd = (unsigned short*)(ws + (size_t)(32u << 20));   //  8 MiB
    unsigned short* Oimg = (unsigned short*)(ws + (size_t)(32u << 20));   //  2 MiB (after fwd)
    unsigned short* Xp   = (unsigned short*)(ws + (size_t)(40u << 20));   // 16 MiB (bf16)
    unsigned short* Einv = (unsigned short*)(ws);                         //  8 MiB (after fwd)

    prep_k<<<10240, 256, 0, stream>>>(x, Xbf, Efwd);
    fwd_gemm_k<<<512, 256, 0, stream>>>(Xbf, Efwd, Xp);
    mlp_k<<<256, 256, 0, stream>>>(Xp, w1, b1, w2, b2, Oimg);
    build_einv_k<<<2048, 256, 0, stream>>>(Einv);
    inv_gemm_k<<<1024, 256, 0, stream>>>(x, Einv, Oimg, out);
}

// Round 4
// 88.713 us; speedup vs baseline: 18.7928x; 1.2280x over previous
//
#include <hip/hip_runtime.h>
#include <math.h>

#define RS 0.011048543456039806f   // 1/sqrt(8192)

typedef short short8 __attribute__((ext_vector_type(8)));
typedef float f32x4 __attribute__((ext_vector_type(4)));

static __device__ __forceinline__ unsigned short f2bf(float f) {
    unsigned int b = __float_as_uint(f);
    b += 0x7FFF + ((b >> 16) & 1);   // RNE
    return (unsigned short)(b >> 16);
}
static __device__ __forceinline__ float bf2f(unsigned short u) {
    return __uint_as_float(((unsigned int)u) << 16);
}
static __device__ __forceinline__ float gelu_exact(float v) {
    return 0.5f * v * (1.0f + erff(v * 0.70710678118654752f));
}
static __device__ __forceinline__ void gload_lds16(const void* g, void* l) {
    __builtin_amdgcn_global_load_lds((const __attribute__((address_space(1))) void*)g,
                                     (__attribute__((address_space(3))) void*)l, 16, 0, 0);
}

// ---------------------------------------------------------------------------
// Fragment-image layout per 128x64 tile (16 KiB), shared by ALL operands:
//   byte = (f*64 + l)*16 + j*2,  f = rowgrp*2 + kk
//   row  = rowgrp*16 + (l&15),   k = kk*32 + (l>>4)*8 + j
// A and B tiles use the same (f,l,j)->k slot map -> invariant to HW k-perm.
// ---------------------------------------------------------------------------

// prep (grid 7168):
//  [0,4096):    x -> folded x_s/x_d bf16 B-images (Xbf: [b][sd][nt][T] tiles)
//  [4096,5120): Efwd builder (folded: 512 rows x K=4096; Re=cos, Im=-sin)
//  [5120,7168): Einv builder (unfolded: 8192 x 512)
__global__ void prep_k(const float* __restrict__ x,
                       unsigned short* __restrict__ Xbf,
                       unsigned short* __restrict__ Efwd,
                       unsigned short* __restrict__ Einv) {
    const int bid = blockIdx.x, tid = threadIdx.x;
    if (bid < 4096) {
        const int gid = bid * 256 + tid;              // 0..1048575
        const int l = gid & 63;
        const int f = (gid >> 6) & 15;
        const int tp = gid >> 10;                     // (b*2+nt)*64+T
        const int T = tp & 63, nt = (tp >> 6) & 1, b = tp >> 7;
        const int w0 = T * 64 + (f & 1) * 32 + ((l >> 4) << 3);
        const int c = nt * 128 + ((f >> 1) << 4) + (l & 15);
        const float* xp = x + ((size_t)b * 8192) * 256 + c;
        short8 vs, vd;
#pragma unroll
        for (int j = 0; j < 8; ++j) {
            const int w = w0 + j;
            const float xa = xp[(size_t)w * 256];
            const float xb = w ? xp[(size_t)(8192 - w) * 256] : 0.0f;
            vs[j] = (short)f2bf(xa + xb);
            vd[j] = (short)f2bf(w ? xa - xb : 0.0f);
        }
        const size_t in_tile = (size_t)(f * 64 + l) * 8;
        *(short8*)(Xbf + ((size_t)(((b * 2 + 0) * 2 + nt) * 64 + T) * 8192 + in_tile)) = vs;
        *(short8*)(Xbf + ((size_t)(((b * 2 + 1) * 2 + nt) * 64 + T) * 8192 + in_tile)) = vd;
    } else if (bid < 5120) {
        const int gid = (bid - 4096) * 256 + tid;     // 0..262143
        const int l = gid & 63;
        const int f = (gid >> 6) & 15;
        const int T = (gid >> 10) & 63;
        const int I = gid >> 16;                      // 0..3
        const int r = I * 128 + ((f >> 1) << 4) + (l & 15);   // 0..511
        const int m = r & 255;
        const int w0 = T * 64 + (f & 1) * 32 + ((l >> 4) << 3);
        short8 v;
#pragma unroll
        for (int j = 0; j < 8; ++j) {
            int mw = (m * (w0 + j)) & 8191;
            float s, c;
            sincospif((float)mw * (2.0f / 8192.0f), &s, &c);
            v[j] = (short)f2bf(r < 256 ? RS * c : -RS * s);
        }
        *(short8*)(Efwd + (size_t)gid * 8) = v;
    } else {
        const int gid = (bid - 5120) * 256 + tid;     // 0..524287
        const int l = gid & 63;
        const int f = (gid >> 6) & 15;
        const int T = (gid >> 10) & 7;                // k-step tile 0..7
        const int I = gid >> 13;                      // row tile 0..63
        const int w = I * 128 + ((f >> 1) << 4) + (l & 15);   // 0..8191
        const int k0 = T * 64 + (f & 1) * 32 + ((l >> 4) << 3);
        short8 v;
#pragma unroll
        for (int j = 0; j < 8; ++j) {
            const int k = k0 + j;
            const int m = k & 255;
            int mw = (m * w) & 8191;
            float s, c;
            sincospif((float)mw * (2.0f / 8192.0f), &s, &c);
            float val;
            if (k < 256) val = (m == 0 ? 1.0f : 2.0f) * RS * c;   // re (DC x1)
            else         val = (m == 0 ? 0.0f : -2.0f) * RS * s;  // im
            v[j] = (short)f2bf(val);
        }
        *(short8*)(Einv + (size_t)gid * 8) = v;
    }
}

// ---------------------------------------------------------------------------
// Forward GEMM (folded, K=4096): Xp[ks][b][512][256] bf16.
// grid 512: bid = ks + 8*I + 32*nt + 64*b. Rows I<2: cos*x_s; I>=2: -sin*x_d.
// ---------------------------------------------------------------------------
__launch_bounds__(256, 2)
__global__ void fwd_gemm_k(const unsigned short* __restrict__ Xbf,
                           const unsigned short* __restrict__ Efwd,
                           unsigned short* __restrict__ Xp) {
    __shared__ short8 As8[1024];
    __shared__ short8 Bs8[1024];
    const int tid = threadIdx.x;
    const int lane = tid & 63, wid = tid >> 6;
    const int bid = blockIdx.x;
    const int ks = bid & 7, I = (bid >> 3) & 3, nt = (bid >> 5) & 1, b = bid >> 6;
    const int sd = I >> 1;
    const int wr = wid >> 1, wc = wid & 1;

    f32x4 acc[4][4] = {};

    for (int s = 0; s < 8; ++s) {
        const int T = ks * 8 + s;
        if (s) __syncthreads();
        const char* asrc = (const char*)Efwd + (size_t)(I * 64 + T) * 16384;
        const char* bsrc = (const char*)Xbf + (size_t)(((b * 2 + sd) * 2 + nt) * 64 + T) * 16384;
#pragma unroll
        for (int p = 0; p < 4; ++p) {
            gload_lds16(asrc + p * 4096 + tid * 16, (char*)As8 + p * 4096 + wid * 1024);
            gload_lds16(bsrc + p * 4096 + tid * 16, (char*)Bs8 + p * 4096 + wid * 1024);
        }
        __syncthreads();
#pragma unroll
        for (int kk = 0; kk < 2; ++kk) {
            short8 af[4], bf[4];
#pragma unroll
            for (int i = 0; i < 4; ++i) {
                af[i] = As8[((wr * 4 + i) * 2 + kk) * 64 + lane];
                bf[i] = Bs8[((wc * 4 + i) * 2 + kk) * 64 + lane];
            }
#pragma unroll
            for (int mi = 0; mi < 4; ++mi)
#pragma unroll
                for (int ni = 0; ni < 4; ++ni)
                    acc[mi][ni] = __builtin_amdgcn_mfma_f32_16x16x32_bf16(
                        af[mi], bf[ni], acc[mi][ni], 0, 0, 0);
        }
    }
    // C/D layout: col=lane&15, row=(lane>>4)*4+reg  [m89-verified]
    unsigned short* Xpb = Xp + (size_t)(ks * 8 + b) * 512 * 256;
    const int row0 = I * 128 + wr * 64 + ((lane >> 4) << 2);
    const int colb = nt * 128 + wc * 64 + (lane & 15);
#pragma unroll
    for (int mi = 0; mi < 4; ++mi)
#pragma unroll
        for (int ni = 0; ni < 4; ++ni) {
            const int row = row0 + mi * 16;
            const int col = colb + ni * 16;
#pragma unroll
            for (int r = 0; r < 4; ++r)
                Xpb[(size_t)(row + r) * 256 + col] = f2bf(acc[mi][ni][r]);
        }
}

// ---------------------------------------------------------------------------
// MLP: sum 8 bf16 partials + exact x[4096]*(-1)^m DC-pair term -> complex
// block-diag MLP -> O bf16 in inverse B fragment image. grid 256.
// ---------------------------------------------------------------------------
__launch_bounds__(256, 2)
__global__ void mlp_k(const float* __restrict__ x,
                      const unsigned short* __restrict__ Xp,
                      const float* __restrict__ w1, const float* __restrict__ b1,
                      const float* __restrict__ w2, const float* __restrict__ b2,
                      unsigned short* __restrict__ Oimg) {
    __shared__ float xs[2][8][256];
    __shared__ float o1s[2][8][256];
    const int tid = threadIdx.x;
    const int b = blockIdx.x >> 5;
    const int m0 = (blockIdx.x & 31) * 8;

    {   // stage: thread handles 16 consecutive channels of one (plane, t) row
        const int c = (tid * 16) & 255;
        const int t = (tid >> 4) & 7;
        const int plane = tid >> 7;
        float a[16];
#pragma unroll
        for (int j = 0; j < 16; ++j) a[j] = 0.0f;
#pragma unroll
        for (int ksp = 0; ksp < 8; ++ksp) {
            const unsigned short* p =
                Xp + ((size_t)(ksp * 8 + b) * 512 + plane * 256 + m0 + t) * 256 + c;
            const short8 v0 = *(const short8*)p;
            const short8 v1 = *(const short8*)(p + 8);
#pragma unroll
            for (int j = 0; j < 8; ++j) {
                a[j] += bf2f((unsigned short)v0[j]);
                a[8 + j] += bf2f((unsigned short)v1[j]);
            }
        }
        if (plane == 0) {   // Re X[m] += RS*(-1)^m * x[b,4096,c]
            const float sgn = ((m0 + t) & 1) ? -RS : RS;
            const float* x4 = x + ((size_t)b * 8192 + 4096) * 256 + c;
#pragma unroll
            for (int j = 0; j < 16; ++j) a[j] += sgn * x4[j];
        }
#pragma unroll
        for (int j = 0; j < 16; ++j) xs[plane][t][c + j] = a[j];
    }
    __syncthreads();

    const int n = tid >> 5, oj = tid & 31;
    const float* w1r = w1 + (size_t)n * 1024;
    const float* w1i = w1 + (size_t)(8 + n) * 1024;
    const float b1r = b1[n * 32 + oj], b1i = b1[(8 + n) * 32 + oj];
#pragma unroll
    for (int t = 0; t < 8; ++t) {
        float sr = b1r, si = b1i;
#pragma unroll 8
        for (int i = 0; i < 32; ++i) {
            const float xr = xs[0][t][n * 32 + i];
            const float xi = xs[1][t][n * 32 + i];
            const float wr = w1r[i * 32 + oj];
            const float wi = w1i[i * 32 + oj];
            sr = fmaf(xr, wr, sr); sr = fmaf(xi, -wi, sr);
            si = fmaf(xi, wr, si); si = fmaf(xr, wi, si);
        }
        o1s[0][t][tid] = gelu_exact(sr);
        o1s[1][t][tid] = gelu_exact(si);
    }
    __syncthreads();

    const float* w2r = w2 + (size_t)n * 1024;
    const float* w2i = w2 + (size_t)(8 + n) * 1024;
    const float b2r = b2[n * 32 + oj], b2i = b2[(8 + n) * 32 + oj];
    const int c = tid;
#pragma unroll
    for (int t = 0; t < 8; ++t) {
        float sr = b2r, si = b2i;
#pragma unroll 8
        for (int i = 0; i < 32; ++i) {
            const float pr = o1s[0][t][n * 32 + i];
            const float pi = o1s[1][t][n * 32 + i];
            const float wr = w2r[i * 32 + oj];
            const float wi = w2i[i * 32 + oj];
            sr = fmaf(pr, wr, sr); sr = fmaf(pi, -wi, sr);
            si = fmaf(pi, wr, si); si = fmaf(pr, wi, si);
        }
        const int m = m0 + t;
#pragma unroll
        for (int plane = 0; plane < 2; ++plane) {
            const int k = plane * 256 + m;
            const float val = plane ? si : sr;
            const size_t off =
                ((((size_t)(b * 2 + (c >> 7)) * 8 + (k >> 6)) * 16 +
                  (((c >> 4) & 7) * 2 + ((k >> 5) & 1))) * 64 +
                 (((k >> 3) & 3) * 16 + (c & 15))) * 16 + (k & 7) * 2;
            *(unsigned short*)((char*)Oimg + off) = f2bf(val);
        }
    }
}

// ---------------------------------------------------------------------------
// Inverse GEMM + residual. grid 1024: bid = nt + 2*I + 128*b. K=512.
// Epilogue: acc -> padded LDS -> coalesced float4 x-add + store.
// ---------------------------------------------------------------------------
__launch_bounds__(256, 4)
__global__ void inv_gemm_k(const float* __restrict__ x,
                           const unsigned short* __restrict__ Einv,
                           const unsigned short* __restrict__ Oimg,
                           float* __restrict__ out) {
    __shared__ float smem[64 * 132];                 // 33792 B (aliased below)
    short8* As8 = (short8*)smem;                     // 16 KiB
    short8* Bs8 = ((short8*)smem) + 1024;            // 16 KiB
    const int tid = threadIdx.x;
    const int lane = tid & 63, wid = tid >> 6;
    const int bid = blockIdx.x;
    const int nt = bid & 1, I = (bid >> 1) & 63, b = bid >> 7;
    const int wr = wid >> 1, wc = wid & 1;

    f32x4 acc[4][4] = {};

    for (int T = 0; T < 8; ++T) {
        if (T) __syncthreads();
        const char* asrc = (const char*)Einv + (size_t)(I * 8 + T) * 16384;
        const char* bsrc = (const char*)Oimg + (size_t)((b * 2 + nt) * 8 + T) * 16384;
#pragma unroll
        for (int p = 0; p < 4; ++p) {
            gload_lds16(asrc + p * 4096 + tid * 16, (char*)As8 + p * 4096 + wid * 1024);
            gload_lds16(bsrc + p * 4096 + tid * 16, (char*)Bs8 + p * 4096 + wid * 1024);
        }
        __syncthreads();
#pragma unroll
        for (int kk = 0; kk < 2; ++kk) {
            short8 af[4], bf[4];
#pragma unroll
            for (int i = 0; i < 4; ++i) {
                af[i] = As8[((wr * 4 + i) * 2 + kk) * 64 + lane];
                bf[i] = Bs8[((wc * 4 + i) * 2 + kk) * 64 + lane];
            }
#pragma unroll
            for (int mi = 0; mi < 4; ++mi)
#pragma unroll
                for (int ni = 0; ni < 4; ++ni)
                    acc[mi][ni] = __builtin_amdgcn_mfma_f32_16x16x32_bf16(
                        af[mi], bf[ni], acc[mi][ni], 0, 0, 0);
        }
    }

    // Two-half epilogue: waves with wr==h dump 64x128 acc into padded LDS,
    // then all 256 threads do float4 load-x / add / store-out (128B lines).
    const size_t base = (size_t)b * 8192 * 256 + (size_t)(I * 128) * 256 + nt * 128;
#pragma unroll
    for (int h = 0; h < 2; ++h) {
        __syncthreads();
        if (wr == h) {
#pragma unroll
            for (int mi = 0; mi < 4; ++mi) {
                const int rr = ((lane >> 4) << 2) + mi * 16;
#pragma unroll
                for (int ni = 0; ni < 4; ++ni) {
                    const int cc = wc * 64 + ni * 16 + (lane & 15);
#pragma unroll
                    for (int r = 0; r < 4; ++r)
                        smem[(rr + r) * 132 + cc] = acc[mi][ni][r];
                }
            }
        }
        __syncthreads();
#pragma unroll
        for (int k = 0; k < 8; ++k) {
            const int t = k * 256 + tid;             // 0..2047
            const int row = t >> 5, c4 = (t & 31) << 2;
            const size_t g = base + (size_t)(h * 64 + row) * 256 + c4;
            const float4 xv = *(const float4*)(x + g);
            float4 v = *(const float4*)(&smem[row * 132 + c4]);
            v.x += xv.x; v.y += xv.y; v.z += xv.z; v.w += xv.w;
            *(float4*)(out + g) = v;
        }
    }
}

extern "C" void kernel_launch(void* const* d_in, const int* in_sizes, int n_in,
                              void* d_out, int out_size, void* d_ws, size_t ws_size,
                              hipStream_t stream) {
    const float* x  = (const float*)d_in[0];
    const float* w1 = (const float*)d_in[1];
    const float* b1 = (const float*)d_in[2];
    const float* w2 = (const float*)d_in[3];
    const float* b2 = (const float*)d_in[4];
    float* out = (float*)d_out;

    char* ws = (char*)d_ws;
    unsigned short* Xbf  = (unsigned short*)(ws);                        // 32 MiB (x_s/x_d images)
    unsigned short* Efwd = (unsigned short*)(ws + (32ull << 20));        //  4 MiB
    unsigned short* Einv = (unsigned short*)(ws + (36ull << 20));        //  8 MiB
    unsigned short* Oimg = (unsigned short*)(ws + (44ull << 20));        //  2 MiB
    unsigned short* Xp   = (unsigned short*)(ws + (46ull << 20));        // 16 MiB  (total 62 MiB)

    prep_k<<<7168, 256, 0, stream>>>(x, Xbf, Efwd, Einv);
    fwd_gemm_k<<<512, 256, 0, stream>>>(Xbf, Efwd, Xp);
    mlp_k<<<256, 256, 0, stream>>>(x, Xp, w1, b1, w2, b2, Oimg);
    inv_gemm_k<<<1024, 256, 0, stream>>>(x, Einv, Oimg, out);
}